// Round 11
// baseline (304.909 us; speedup 1.0000x reference)
//
#include <hip/hip_runtime.h>
#include <math.h>

#define LVL 16
#define TBL 65536
#define BATCH 8
#define NPIX 65536       // 256*256
#define SDIM 512
#define HPRIME 2654435761u

typedef __attribute__((ext_vector_type(2))) float f32x2;

struct ResPack { int r[LVL]; };

// ws layout (floats): [0, 17152) weff (8 batches x 2144, paired layout)
#define WEFF_STRIDE 2144

// ---------------------------------------------------------------------------
// Kernel A: fused style + demod + weff emit (ran clean rounds 5/7/9/10).
// ---------------------------------------------------------------------------
__global__ __launch_bounds__(256) void weff_kernel(
    const float* __restrict__ s,
    const float* __restrict__ aw0, const float* __restrict__ ab0,
    const float* __restrict__ aw1, const float* __restrict__ ab1,
    const float* __restrict__ aw2, const float* __restrict__ ab2,
    const float* __restrict__ w0, const float* __restrict__ w1,
    const float* __restrict__ w2,
    float* __restrict__ ws)
{
    const int b = blockIdx.x & 7;
    const int l = blockIdx.x >> 3;
    const int tid = (int)threadIdx.x;
    const int wave = tid >> 6, lane = tid & 63;

    const float* aw; const float* ab; const float* w; int nout;
    if (l == 0)      { aw = aw0; ab = ab0; w = w0; nout = 32; }
    else if (l == 1) { aw = aw1; ab = ab1; w = w1; nout = 32; }
    else             { aw = aw2; ab = ab2; w = w2; nout = 3;  }

    __shared__ float st[32];
    __shared__ float dem[32];

    // ---- style: 32 rows x dot(512). 4 waves x 8 rows, 2 chains per iter.
    const float* sb = s + b * SDIM;
    for (int r0 = wave * 8; r0 < wave * 8 + 8; r0 += 2) {
        const float* rowA = aw + (size_t)r0 * SDIM;
        const float* rowB = aw + (size_t)(r0 + 1) * SDIM;
        float a0 = 0.f, a1 = 0.f;
        #pragma unroll
        for (int j = 0; j < SDIM / 64; ++j) {
            const int k = lane + j * 64;
            const float sv = sb[k];
            a0 += sv * rowA[k];
            a1 += sv * rowB[k];
        }
        #pragma unroll
        for (int off = 32; off >= 1; off >>= 1) {
            a0 += __shfl_xor(a0, off, 64);
            a1 += __shfl_xor(a1, off, 64);
        }
        if (lane == 0) { st[r0] = a0 + ab[r0]; st[r0 + 1] = a1 + ab[r0 + 1]; }
    }
    __syncthreads();

    // ---- demod
    {
        const int o = tid >> 3, sub = tid & 7;
        if (o < nout) {
            float sum = 0.f;
            #pragma unroll
            for (int j = 0; j < 4; ++j) {
                const int i = sub * 4 + j;
                const float v = w[o * 32 + i] * st[i];
                sum += v * v;
            }
            sum += __shfl_xor(sum, 4, 64);
            sum += __shfl_xor(sum, 2, 64);
            sum += __shfl_xor(sum, 1, 64);
            if (sub == 0) dem[o] = 1.0f / sqrtf(sum + 1e-8f);
        }
    }
    __syncthreads();

    // ---- emit paired layout
    float* outp = ws + (size_t)b * WEFF_STRIDE;
    if (l < 2) {
        const int base = l * 1024;
        for (int idx = tid; idx < 1024; idx += 256) {
            const int o2 = idx >> 6, rem = idx & 63, i = rem >> 1, h = rem & 1;
            const int oo = o2 + 16 * h;
            outp[base + idx] = w[oo * 32 + i] * st[i] * dem[oo];
        }
    } else {
        if (tid < 96) {
            const int oo = tid >> 5, i = tid & 31;
            outp[2048 + tid] = w[tid] * st[i] * dem[oo];
        }
    }
}

// ---------------------------------------------------------------------------
// Kernel B: round-9 verified base (1 px/thread, 2048 blocks, no LDS) with ONE
// structural change aimed at OCCUPANCY: layer-0 is streamed in 2-level groups
// (8 gathers in flight -> blend 4 feats -> fold into the 16 paired
// accumulators, ascending i), eliminating the feat[32] array; combined with
// __launch_bounds__(256, 8) this targets VGPR <= 64 => 8 waves/SIMD
// (vs 6 at VGPR 80), full 2048-block single-round residency, 33% more
// latency-hiding streams. Accumulation order bit-identical to the verified
// kernel (bias, then i = 0..31 ascending). L1/L2 = round-9 form, untouched.
// ---------------------------------------------------------------------------
__global__ __launch_bounds__(256, 8) void fused_kernel(
    const float* __restrict__ tables,   // [B, L, T, 2]
    const float* __restrict__ coords,   // [N, 2]
    const float* __restrict__ weff,     // ws: paired weights per batch
    const float* __restrict__ b0, const float* __restrict__ b1, const float* __restrict__ b2,
    float* __restrict__ out,            // [B, 3, 256, 256]
    ResPack res)
{
    const int b     = blockIdx.x & 7;           // XCD-affinity: batch <-> XCD
    const int chunk = blockIdx.x >> 3;
    const int n     = chunk * 256 + (int)threadIdx.x;

    const float cx = coords[2 * n];
    const float cy = coords[2 * n + 1];
    const float* tb = tables + (size_t)b * (LVL * TBL * 2);

    const f32x2* W0p = (const f32x2*)(weff + (size_t)b * WEFF_STRIDE);         // [16][32]
    const f32x2* W1p = W0p + 512;                                              // [16][32]
    const float* W2  = weff + (size_t)b * WEFF_STRIDE + 2048;                  // [3][32]

    // layer-0 accumulators (paired outputs {o2, o2+16})
    f32x2 h1p[16];
    #pragma unroll
    for (int o2 = 0; o2 < 16; ++o2) { h1p[o2][0] = b0[o2]; h1p[o2][1] = b0[o2 + 16]; }

    // ---- streamed gather + layer-0 fold: 2 levels (8 gathers, 4 feats)/group
    #pragma unroll
    for (int lg = 0; lg < 8; ++lg) {
        float2 g[8];
        float fxs[2], fys[2];

        #pragma unroll
        for (int j = 0; j < 2; ++j) {
            const int l = lg * 2 + j;
            const int R = res.r[l];
            const float rm1 = (float)(R - 1);
            const float px = cx * rm1, py = cy * rm1;
            const float fpx = floorf(px), fpy = floorf(py);
            fxs[j] = px - fpx; fys[j] = py - fpy;
            unsigned x0 = (unsigned)fpx, y0 = (unsigned)fpy;
            const unsigned im = (unsigned)(R - 1);
            unsigned x1 = x0 + 1u; if (x1 > im) x1 = im;
            unsigned y1 = y0 + 1u; if (y1 > im) y1 = im;
            const unsigned hy0 = y0 * HPRIME, hy1 = y1 * HPRIME;
            const float2* tl = (const float2*)(tb + l * (TBL * 2));
            g[4 * j + 0] = tl[(x0 ^ hy0) & 0xFFFFu];
            g[4 * j + 1] = tl[(x1 ^ hy0) & 0xFFFFu];
            g[4 * j + 2] = tl[(x0 ^ hy1) & 0xFFFFu];
            g[4 * j + 3] = tl[(x1 ^ hy1) & 0xFFFFu];
        }

        float f[4];
        #pragma unroll
        for (int j = 0; j < 2; ++j) {
            const float fx = fxs[j], fy = fys[j];
            const float w00 = (1.f - fx) * (1.f - fy);
            const float w10 = fx * (1.f - fy);
            const float w01 = (1.f - fx) * fy;
            const float w11 = fx * fy;
            const float2 g00 = g[4 * j + 0];
            const float2 g10 = g[4 * j + 1];
            const float2 g01 = g[4 * j + 2];
            const float2 g11 = g[4 * j + 3];
            f[2 * j]     = g00.x * w00 + g10.x * w10 + g01.x * w01 + g11.x * w11;
            f[2 * j + 1] = g00.y * w00 + g10.y * w10 + g01.y * w01 + g11.y * w11;
        }

        // fold features i = 4*lg .. 4*lg+3 into all paired accumulators
        #pragma unroll
        for (int o2 = 0; o2 < 16; ++o2) {
            #pragma unroll
            for (int k = 0; k < 4; ++k) {
                f32x2 t; t[0] = f[k]; t[1] = f[k];
                h1p[o2] += W0p[o2 * 32 + 4 * lg + k] * t;
            }
        }
    }

    // relu
    #pragma unroll
    for (int o2 = 0; o2 < 16; ++o2) {
        h1p[o2][0] = fmaxf(h1p[o2][0], 0.f);
        h1p[o2][1] = fmaxf(h1p[o2][1], 0.f);
    }

    // layer 1 (round-9 verified form)
    f32x2 h2p[16];
    #pragma unroll
    for (int o2 = 0; o2 < 16; ++o2) {
        f32x2 acc; acc[0] = b1[o2]; acc[1] = b1[o2 + 16];
        #pragma unroll
        for (int i = 0; i < 32; ++i) {
            const float hv = h1p[i & 15][i >> 4];
            f32x2 fb; fb[0] = hv; fb[1] = hv;
            acc += W1p[o2 * 32 + i] * fb;
        }
        acc[0] = fmaxf(acc[0], 0.f); acc[1] = fmaxf(acc[1], 0.f);
        h2p[o2] = acc;
    }

    // layer 2 (3 outputs, scalar)
    #pragma unroll
    for (int o = 0; o < 3; ++o) {
        float acc = b2[o];
        #pragma unroll
        for (int i = 0; i < 32; ++i)
            acc = fmaf(W2[o * 32 + i], h2p[i & 15][i >> 4], acc);
        out[((size_t)(b * 3 + o) << 16) + n] = tanhf(acc);
    }
}

// ---------------------------------------------------------------------------
extern "C" void kernel_launch(void* const* d_in, const int* in_sizes, int n_in,
                              void* d_out, int out_size, void* d_ws, size_t ws_size,
                              hipStream_t stream) {
    const float* x      = (const float*)d_in[0];
    const float* s      = (const float*)d_in[1];
    const float* coords = (const float*)d_in[2];
    const float* w0  = (const float*)d_in[3];
    const float* aw0 = (const float*)d_in[4];
    const float* ab0 = (const float*)d_in[5];
    const float* b0  = (const float*)d_in[6];
    const float* w1  = (const float*)d_in[7];
    const float* aw1 = (const float*)d_in[8];
    const float* ab1 = (const float*)d_in[9];
    const float* b1  = (const float*)d_in[10];
    const float* w2  = (const float*)d_in[11];
    const float* aw2 = (const float*)d_in[12];
    const float* ab2 = (const float*)d_in[13];
    const float* b2  = (const float*)d_in[14];
    float* out = (float*)d_out;
    float* ws  = (float*)d_ws;    // 17152 floats used

    ResPack rp;
    const double g = pow(256.0 / 16.0, 1.0 / 15.0);
    for (int l = 0; l < LVL; ++l) {
        double r = 16.0 * pow(g, (double)l);
        long ri = lround(r);
        if (ri > 256) ri = 256;
        rp.r[l] = (int)ri;
    }

    hipLaunchKernelGGL(weff_kernel, dim3(24), dim3(256), 0, stream,
                       s, aw0, ab0, aw1, ab1, aw2, ab2, w0, w1, w2, ws);
    hipLaunchKernelGGL(fused_kernel, dim3(NPIX / 256 * BATCH), dim3(256), 0, stream,
                       x, coords, ws, b0, b1, b2, out, rp);
}

// Round 12
// 164.624 us; speedup vs baseline: 1.8522x; 1.8522x over previous
//
#include <hip/hip_runtime.h>
#include <math.h>

#define LVL 16
#define TBL 65536
#define BATCH 8
#define NPIX 65536       // 256*256
#define SDIM 512
#define HPRIME 2654435761u

typedef __attribute__((ext_vector_type(2))) float f32x2;

struct ResPack { int r[LVL]; };

// ws layout (floats): [0, 17152) weff (8 batches x 2144, paired layout)
#define WEFF_STRIDE 2144

// ---------------------------------------------------------------------------
// Kernel A: fused style + demod + weff emit (ran clean rounds 5/7/9/10).
// Grid 24 blocks: b = blk&7, l = blk>>3 (layer). Each block computes its
// layer's 32 style dots, demod, and emits its weff slice (paired layout).
// ---------------------------------------------------------------------------
__global__ __launch_bounds__(256) void weff_kernel(
    const float* __restrict__ s,
    const float* __restrict__ aw0, const float* __restrict__ ab0,
    const float* __restrict__ aw1, const float* __restrict__ ab1,
    const float* __restrict__ aw2, const float* __restrict__ ab2,
    const float* __restrict__ w0, const float* __restrict__ w1,
    const float* __restrict__ w2,
    float* __restrict__ ws)
{
    const int b = blockIdx.x & 7;
    const int l = blockIdx.x >> 3;
    const int tid = (int)threadIdx.x;
    const int wave = tid >> 6, lane = tid & 63;

    const float* aw; const float* ab; const float* w; int nout;
    if (l == 0)      { aw = aw0; ab = ab0; w = w0; nout = 32; }
    else if (l == 1) { aw = aw1; ab = ab1; w = w1; nout = 32; }
    else             { aw = aw2; ab = ab2; w = w2; nout = 3;  }

    __shared__ float st[32];
    __shared__ float dem[32];

    // ---- style: 32 rows x dot(512). 4 waves x 8 rows, 2 chains per iter.
    const float* sb = s + b * SDIM;
    for (int r0 = wave * 8; r0 < wave * 8 + 8; r0 += 2) {
        const float* rowA = aw + (size_t)r0 * SDIM;
        const float* rowB = aw + (size_t)(r0 + 1) * SDIM;
        float a0 = 0.f, a1 = 0.f;
        #pragma unroll
        for (int j = 0; j < SDIM / 64; ++j) {
            const int k = lane + j * 64;
            const float sv = sb[k];
            a0 += sv * rowA[k];
            a1 += sv * rowB[k];
        }
        #pragma unroll
        for (int off = 32; off >= 1; off >>= 1) {
            a0 += __shfl_xor(a0, off, 64);
            a1 += __shfl_xor(a1, off, 64);
        }
        if (lane == 0) { st[r0] = a0 + ab[r0]; st[r0 + 1] = a1 + ab[r0 + 1]; }
    }
    __syncthreads();

    // ---- demod: o = tid>>3 (0..31), 8 lanes each sum 4 squares + butterfly.
    {
        const int o = tid >> 3, sub = tid & 7;
        if (o < nout) {
            float sum = 0.f;
            #pragma unroll
            for (int j = 0; j < 4; ++j) {
                const int i = sub * 4 + j;
                const float v = w[o * 32 + i] * st[i];
                sum += v * v;
            }
            sum += __shfl_xor(sum, 4, 64);
            sum += __shfl_xor(sum, 2, 64);
            sum += __shfl_xor(sum, 1, 64);
            if (sub == 0) dem[o] = 1.0f / sqrtf(sum + 1e-8f);
        }
    }
    __syncthreads();

    // ---- emit paired layout (same formulas/order as the verified kernel).
    float* outp = ws + (size_t)b * WEFF_STRIDE;
    if (l < 2) {
        const int base = l * 1024;
        for (int idx = tid; idx < 1024; idx += 256) {
            const int o2 = idx >> 6, rem = idx & 63, i = rem >> 1, h = rem & 1;
            const int oo = o2 + 16 * h;
            outp[base + idx] = w[oo * 32 + i] * st[i] * dem[oo];
        }
    } else {
        if (tid < 96) {
            const int oo = tid >> 5, i = tid & 31;
            outp[2048 + tid] = w[tid] * st[i] * dem[oo];
        }
    }
}

// ---------------------------------------------------------------------------
// Kernel B: verified round-9 kernel (51.9 us on HW). 1 px/thread, 2048
// blocks, no LDS, no barriers. Gather phase batches 4 levels (16 loads in
// flight); MLP = paired-packed fp32. VGPR 80 -> 16 waves/CU; this is the
// measured optimum of the family (occupancy-forcing spills: r11; coop-LDS,
// 2-px/thread, wider batching, float4 weights: all measured worse or null).
// ---------------------------------------------------------------------------
__global__ __launch_bounds__(256) void fused_kernel(
    const float* __restrict__ tables,   // [B, L, T, 2]
    const float* __restrict__ coords,   // [N, 2]
    const float* __restrict__ weff,     // ws: paired weights per batch
    const float* __restrict__ b0, const float* __restrict__ b1, const float* __restrict__ b2,
    float* __restrict__ out,            // [B, 3, 256, 256]
    ResPack res)
{
    const int b     = blockIdx.x & 7;           // XCD-affinity: batch <-> XCD
    const int chunk = blockIdx.x >> 3;
    const int n     = chunk * 256 + (int)threadIdx.x;

    const float cx = coords[2 * n];
    const float cy = coords[2 * n + 1];
    const float* tb = tables + (size_t)b * (LVL * TBL * 2);

    float feat[32];

    // ---- gather phase: groups of 4 levels, 16 loads in flight per group ----
    #pragma unroll
    for (int lg = 0; lg < 4; ++lg) {
        float2 g[16];
        float fxs[4], fys[4];

        #pragma unroll
        for (int j = 0; j < 4; ++j) {
            const int l = lg * 4 + j;
            const int R = res.r[l];
            const float rm1 = (float)(R - 1);
            const float px = cx * rm1, py = cy * rm1;
            const float fpx = floorf(px), fpy = floorf(py);
            fxs[j] = px - fpx; fys[j] = py - fpy;
            unsigned x0 = (unsigned)fpx, y0 = (unsigned)fpy;
            const unsigned im = (unsigned)(R - 1);
            unsigned x1 = x0 + 1u; if (x1 > im) x1 = im;
            unsigned y1 = y0 + 1u; if (y1 > im) y1 = im;
            const unsigned hy0 = y0 * HPRIME, hy1 = y1 * HPRIME;
            const float2* tl = (const float2*)(tb + l * (TBL * 2));
            g[4 * j + 0] = tl[(x0 ^ hy0) & 0xFFFFu];
            g[4 * j + 1] = tl[(x1 ^ hy0) & 0xFFFFu];
            g[4 * j + 2] = tl[(x0 ^ hy1) & 0xFFFFu];
            g[4 * j + 3] = tl[(x1 ^ hy1) & 0xFFFFu];
        }

        #pragma unroll
        for (int j = 0; j < 4; ++j) {
            const int l = lg * 4 + j;
            const float fx = fxs[j], fy = fys[j];
            const float w00 = (1.f - fx) * (1.f - fy);
            const float w10 = fx * (1.f - fy);
            const float w01 = (1.f - fx) * fy;
            const float w11 = fx * fy;
            const float2 g00 = g[4 * j + 0];
            const float2 g10 = g[4 * j + 1];
            const float2 g01 = g[4 * j + 2];
            const float2 g11 = g[4 * j + 3];
            feat[2 * l]     = g00.x * w00 + g10.x * w10 + g01.x * w01 + g11.x * w11;
            feat[2 * l + 1] = g00.y * w00 + g10.y * w10 + g01.y * w01 + g11.y * w11;
        }
    }

    const f32x2* W0p = (const f32x2*)(weff + (size_t)b * WEFF_STRIDE);         // [16][32]
    const f32x2* W1p = W0p + 512;                                              // [16][32]
    const float* W2  = weff + (size_t)b * WEFF_STRIDE + 2048;                  // [3][32]

    // layer 0: paired outputs {o2, o2+16}
    f32x2 h1p[16];
    #pragma unroll
    for (int o2 = 0; o2 < 16; ++o2) {
        f32x2 acc; acc[0] = b0[o2]; acc[1] = b0[o2 + 16];
        #pragma unroll
        for (int i = 0; i < 32; ++i) {
            f32x2 fb; fb[0] = feat[i]; fb[1] = feat[i];
            acc += W0p[o2 * 32 + i] * fb;
        }
        acc[0] = fmaxf(acc[0], 0.f); acc[1] = fmaxf(acc[1], 0.f);
        h1p[o2] = acc;
    }

    // layer 1
    f32x2 h2p[16];
    #pragma unroll
    for (int o2 = 0; o2 < 16; ++o2) {
        f32x2 acc; acc[0] = b1[o2]; acc[1] = b1[o2 + 16];
        #pragma unroll
        for (int i = 0; i < 32; ++i) {
            const float hv = h1p[i & 15][i >> 4];
            f32x2 fb; fb[0] = hv; fb[1] = hv;
            acc += W1p[o2 * 32 + i] * fb;
        }
        acc[0] = fmaxf(acc[0], 0.f); acc[1] = fmaxf(acc[1], 0.f);
        h2p[o2] = acc;
    }

    // layer 2 (3 outputs, scalar)
    #pragma unroll
    for (int o = 0; o < 3; ++o) {
        float acc = b2[o];
        #pragma unroll
        for (int i = 0; i < 32; ++i)
            acc = fmaf(W2[o * 32 + i], h2p[i & 15][i >> 4], acc);
        out[((size_t)(b * 3 + o) << 16) + n] = tanhf(acc);
    }
}

// ---------------------------------------------------------------------------
extern "C" void kernel_launch(void* const* d_in, const int* in_sizes, int n_in,
                              void* d_out, int out_size, void* d_ws, size_t ws_size,
                              hipStream_t stream) {
    const float* x      = (const float*)d_in[0];
    const float* s      = (const float*)d_in[1];
    const float* coords = (const float*)d_in[2];
    const float* w0  = (const float*)d_in[3];
    const float* aw0 = (const float*)d_in[4];
    const float* ab0 = (const float*)d_in[5];
    const float* b0  = (const float*)d_in[6];
    const float* w1  = (const float*)d_in[7];
    const float* aw1 = (const float*)d_in[8];
    const float* ab1 = (const float*)d_in[9];
    const float* b1  = (const float*)d_in[10];
    const float* w2  = (const float*)d_in[11];
    const float* aw2 = (const float*)d_in[12];
    const float* ab2 = (const float*)d_in[13];
    const float* b2  = (const float*)d_in[14];
    float* out = (float*)d_out;
    float* ws  = (float*)d_ws;    // 17152 floats used

    ResPack rp;
    const double g = pow(256.0 / 16.0, 1.0 / 15.0);
    for (int l = 0; l < LVL; ++l) {
        double r = 16.0 * pow(g, (double)l);
        long ri = lround(r);
        if (ri > 256) ri = 256;
        rp.r[l] = (int)ri;
    }

    hipLaunchKernelGGL(weff_kernel, dim3(24), dim3(256), 0, stream,
                       s, aw0, ab0, aw1, ab1, aw2, ab2, w0, w1, w2, ws);
    hipLaunchKernelGGL(fused_kernel, dim3(NPIX / 256 * BATCH), dim3(256), 0, stream,
                       x, coords, ws, b0, b1, b2, out, rp);
}